// Round 5
// baseline (75.394 us; speedup 1.0000x reference)
//
#include <hip/hip_runtime.h>

#define BS 4
#define DM 1024
#define LL 2048
#define NS 64
#define CC 32        // chunks; s = CC*BS*NS*DM*4 = 32 MB (L3-resident; fits ws)
#define TC 64        // chunk length = LL/CC
#define ROWS 64      // d-rows per block; 128-thread blocks = 64 d x 2 lanes
#define PADS 65      // odd stride -> bank (dl+t)%32, conflict-free
#define NSG 32       // states per lane (lane&1 picks half)

// ---------------- pass 1: chunk-local final states (zero init) ----------------
// 2048 blocks x 128 thr = 8 blocks/CU exactly resident (LDS 16.6KB, VGPR<=128)
__global__ __launch_bounds__(128, 4) void ssm_pass1(const float* __restrict__ u,
                                                    const float* __restrict__ A,
                                                    float* __restrict__ s) {
    __shared__ float tile[ROWS * PADS];
    const int tid = threadIdx.x;
    const int bx  = blockIdx.x;
    const int c   = bx & (CC - 1);
    const int rem = bx >> 5;
    const int b   = rem & (BS - 1);
    const int d0  = (rem >> 2) * ROWS;
    const int dl  = tid >> 1;      // d-row within block (0..63)
    const int grp = tid & 1;       // state half
    const int ib  = NSG * grp;

    // stage u tile (64 x 64): 8 float4 per thread, coalesced
    {
        const float* ubase = u + ((size_t)(b * DM + d0) * LL + c * TC);
#pragma unroll
        for (int k = 0; k < 8; ++k) {
            const int idx = tid + k * 128;
            const int r   = idx >> 4;          // 16 float4 per row
            const int t4  = (idx & 15) * 4;
            const float4 v = *reinterpret_cast<const float4*>(ubase + (size_t)r * LL + t4);
            float* dst = &tile[r * PADS + t4];
            dst[0] = v.x; dst[1] = v.y; dst[2] = v.z; dst[3] = v.w;
        }
    }

    // divergent (grp-dependent) param loads -> VGPR-resident by construction
    float a[NSG];
#pragma unroll
    for (int j = 0; j < NSG; ++j) a[j] = A[(ib + j) * (NS + 1)];

    float g[NSG];
#pragma unroll
    for (int j = 0; j < NSG; ++j) g[j] = 0.f;

    __syncthreads();

    const float* row = &tile[dl * PADS];
#pragma unroll 2
    for (int t = 0; t < TC; ++t) {
        const float uv = row[t];
#pragma unroll
        for (int j = 0; j < NSG; ++j) g[j] = fmaf(a[j], g[j], uv);
    }

    const int d = d0 + dl;
#pragma unroll
    for (int j = 0; j < NSG; ++j)
        s[(((size_t)c * BS + b) * NS + ib + j) * DM + d] = g[j];
}

// ---------------- combine: prefetch-all, scan in-register, store-all ----------------
__global__ void ssm_combine(const float* __restrict__ A, float* __restrict__ s) {
    const int tid = blockIdx.x * blockDim.x + threadIdx.x;  // B*N*D threads
    const int d   = tid & (DM - 1);
    const int rem = tid >> 10;
    const int i   = rem & (NS - 1);
    const int b   = rem >> 6;

    const float a = A[i * (NS + 1)];
    float aT = a;                  // a^TC, TC=64 -> 6 squarings
#pragma unroll
    for (int j = 0; j < 6; ++j) aT *= aT;

    const size_t base   = ((size_t)b * NS + i) * DM + d;
    const size_t cstride = (size_t)BS * NS * DM;

    // all 32 loads are independent -> one latency exposure, not 32
    float v[CC];
#pragma unroll
    for (int c = 0; c < CC; ++c) v[c] = s[base + (size_t)c * cstride];

    float run = 0.f;
#pragma unroll
    for (int c = 0; c < CC; ++c) {
        const float sl = v[c];
        s[base + (size_t)c * cstride] = run;   // true initial state of chunk c
        run = fmaf(aT, run, sl);
    }
}

// ---------------- pass 2: recurrence with true init, produce y ----------------
__global__ __launch_bounds__(128, 4) void ssm_pass2(const float* __restrict__ u,
                                                    const float* __restrict__ A,
                                                    const float* __restrict__ Bv,
                                                    const float* __restrict__ Cv,
                                                    const float* __restrict__ s,
                                                    float* __restrict__ y) {
    __shared__ float tile[ROWS * PADS];
    const int tid = threadIdx.x;
    const int bx  = blockIdx.x;
    const int c   = bx & (CC - 1);
    const int rem = bx >> 5;
    const int b   = rem & (BS - 1);
    const int d0  = (rem >> 2) * ROWS;
    const int dl  = tid >> 1;
    const int grp = tid & 1;
    const int ib  = NSG * grp;

    // stage u tile
    {
        const float* ubase = u + ((size_t)(b * DM + d0) * LL + c * TC);
#pragma unroll
        for (int k = 0; k < 8; ++k) {
            const int idx = tid + k * 128;
            const int r   = idx >> 4;
            const int t4  = (idx & 15) * 4;
            const float4 v = *reinterpret_cast<const float4*>(ubase + (size_t)r * LL + t4);
            float* dst = &tile[r * PADS + t4];
            dst[0] = v.x; dst[1] = v.y; dst[2] = v.z; dst[3] = v.w;
        }
    }

    // divergent param loads -> VGPRs
    float a[NSG], w[NSG];
#pragma unroll
    for (int j = 0; j < NSG; ++j) {
        a[j] = A[(ib + j) * (NS + 1)];
        w[j] = Bv[ib + j] * Cv[ib + j];
    }

    // true chunk-initial states (overlaps with staging latency)
    float g[NSG];
    const int d = d0 + dl;
#pragma unroll
    for (int j = 0; j < NSG; ++j)
        g[j] = s[(((size_t)c * BS + b) * NS + ib + j) * DM + d];

    __syncthreads();

    float* row = &tile[dl * PADS];
#pragma unroll 2
    for (int t = 0; t < TC; ++t) {
        const float uv = row[t];
        float y0 = 0.f, y1 = 0.f;
#pragma unroll
        for (int j = 0; j < NSG; j += 2) {
            g[j + 0] = fmaf(a[j + 0], g[j + 0], uv); y0 = fmaf(w[j + 0], g[j + 0], y0);
            g[j + 1] = fmaf(a[j + 1], g[j + 1], uv); y1 = fmaf(w[j + 1], g[j + 1], y1);
        }
        float yp = y0 + y1;
        yp += __shfl_xor(yp, 1, 64);   // combine the two state-halves of this d
        if (grp == 0) row[t] = yp;     // single-lane LDS write, no aliasing
    }
    __syncthreads();

    // coalesced float4 writeout of y
    {
        float* ybase = y + ((size_t)(b * DM + d0) * LL + c * TC);
#pragma unroll
        for (int k = 0; k < 8; ++k) {
            const int idx = tid + k * 128;
            const int r   = idx >> 4;
            const int t4  = (idx & 15) * 4;
            const float* sp = &tile[r * PADS + t4];
            const float4 v = make_float4(sp[0], sp[1], sp[2], sp[3]);
            *reinterpret_cast<float4*>(ybase + (size_t)r * LL + t4) = v;
        }
    }
}

extern "C" void kernel_launch(void* const* d_in, const int* in_sizes, int n_in,
                              void* d_out, int out_size, void* d_ws, size_t ws_size,
                              hipStream_t stream) {
    const float* u  = (const float*)d_in[0];
    const float* A  = (const float*)d_in[1];
    const float* Bv = (const float*)d_in[2];
    const float* Cv = (const float*)d_in[3];
    float* y = (float*)d_out;
    float* s = (float*)d_ws;

    const int nblocks = CC * BS * (DM / ROWS);   // 2048
    ssm_pass1<<<nblocks, 128, 0, stream>>>(u, A, s);
    ssm_combine<<<(BS * NS * DM) / 256, 256, 0, stream>>>(A, s);
    ssm_pass2<<<nblocks, 128, 0, stream>>>(u, A, Bv, Cv, s, y);
}